// Round 1
// baseline (1047.735 us; speedup 1.0000x reference)
//
#include <hip/hip_runtime.h>

#define N_NODES  100000
#define N_EDGES  1600000
#define N_GRAPHS 256
#define F        64

// ---------- helpers: ordered-uint encoding for float atomicMax ----------
__device__ __forceinline__ unsigned int f2o(float f) {
    unsigned int u = __float_as_uint(f);
    return (u & 0x80000000u) ? ~u : (u | 0x80000000u);
}
__device__ __forceinline__ float o2f(unsigned int u) {
    return (u & 0x80000000u) ? __uint_as_float(u & 0x7fffffffu) : __uint_as_float(~u);
}

// ---------- 1. agg[dst] += x[src]  (wave per edge, lane = feature) ----------
__global__ __launch_bounds__(256) void scatter_add_edges(
        const float* __restrict__ x,
        const int*   __restrict__ src,
        const int*   __restrict__ dst,
        float*       __restrict__ agg) {
    unsigned int gid = blockIdx.x * 256u + threadIdx.x;
    int edge = (int)(gid >> 6);
    int lane = (int)(gid & 63u);
    if (edge >= N_EDGES) return;
    int s = src[edge];   // wave-uniform load (broadcast)
    int d = dst[edge];
    atomicAdd(&agg[d * F + lane], x[s * F + lane]);
}

// ---------- 2. h = relu((x+agg)@Wg + bg); scores = h@Wa + ba ----------
__global__ __launch_bounds__(256) void transform_kernel(
        const float* __restrict__ x,
        const float* __restrict__ agg,
        const float* __restrict__ Wg,   // [64,64] row-major (k, f)
        const float* __restrict__ bg,   // [64]
        const float* __restrict__ Wa,   // [64]
        const float* __restrict__ ba,   // [1]
        float*       __restrict__ h,
        float*       __restrict__ scores) {
    __shared__ float Wlds[F * F];
    __shared__ float blds[F];
    __shared__ float Walds[F];
    int tid = threadIdx.x;
    for (int i = tid; i < F * F; i += 256) Wlds[i] = Wg[i];
    if (tid < F) { blds[tid] = bg[tid]; Walds[tid] = Wa[tid]; }
    __syncthreads();

    int wave = tid >> 6;
    int lane = tid & 63;
    int n = blockIdx.x * 4 + wave;
    if (n >= N_NODES) return;

    float rowv = x[n * F + lane] + agg[n * F + lane];
    float acc = 0.f;
    #pragma unroll
    for (int k = 0; k < F; ++k) {
        float rk = __shfl(rowv, k, 64);
        acc += rk * Wlds[k * F + lane];   // lanes hit stride-1: 2-way bank alias, free
    }
    float hv = acc + blds[lane];
    hv = hv > 0.f ? hv : 0.f;
    h[n * F + lane] = hv;

    float p = hv * Walds[lane];
    #pragma unroll
    for (int off = 32; off > 0; off >>= 1)
        p += __shfl_down(p, off, 64);
    if (lane == 0) scores[n] = p + ba[0];
}

// ---------- 3. per-graph max of scores ----------
__global__ __launch_bounds__(256) void seg_max_kernel(
        const float* __restrict__ scores,
        const int*   __restrict__ batch,
        unsigned int* __restrict__ segmax) {
    int n = blockIdx.x * 256 + threadIdx.x;
    if (n >= N_NODES) return;
    atomicMax(&segmax[batch[n]], f2o(scores[n]));
}

// ---------- 4. e = exp(s - max); denom += e; out_acc += e*h ----------
__global__ __launch_bounds__(256) void pool_kernel(
        const float* __restrict__ h,
        const float* __restrict__ scores,
        const int*   __restrict__ batch,
        const unsigned int* __restrict__ segmax,
        float* __restrict__ denom,
        float* __restrict__ out_acc) {
    unsigned int gid = blockIdx.x * 256u + threadIdx.x;
    int n = (int)(gid >> 6);
    int lane = (int)(gid & 63u);
    if (n >= N_NODES) return;
    int b = batch[n];                       // wave-uniform
    float m = o2f(segmax[b]);
    float e = expf(scores[n] - m);
    if (lane == 0) atomicAdd(&denom[b], e);
    atomicAdd(&out_acc[b * F + lane], e * h[n * F + lane]);
}

// ---------- 5. out /= denom ----------
__global__ __launch_bounds__(256) void finalize_kernel(
        float* __restrict__ out,
        const float* __restrict__ denom) {
    int i = blockIdx.x * 256 + threadIdx.x;
    if (i >= N_GRAPHS * F) return;
    float d = denom[i >> 6];
    out[i] = (d > 0.f) ? out[i] / d : 0.f;
}

extern "C" void kernel_launch(void* const* d_in, const int* in_sizes, int n_in,
                              void* d_out, int out_size, void* d_ws, size_t ws_size,
                              hipStream_t stream) {
    const float* x     = (const float*)d_in[0];
    const int*   ei    = (const int*)d_in[1];   // [2, N_EDGES]
    const int*   batch = (const int*)d_in[2];   // [N_NODES]
    const float* Wg    = (const float*)d_in[3];
    const float* bg    = (const float*)d_in[4];
    const float* Wa    = (const float*)d_in[5];
    const float* ba    = (const float*)d_in[6];
    float* out = (float*)d_out;

    const int* src = ei;
    const int* dst = ei + N_EDGES;

    // workspace layout (bytes)
    char* ws = (char*)d_ws;
    float* agg    = (float*)(ws);                         // 25,600,000 B
    float* h      = (float*)(ws + 25600000);              // 25,600,000 B
    float* scores = (float*)(ws + 51200000);              //    400,000 B
    unsigned int* segmax = (unsigned int*)(ws + 51600000);//      1,024 B
    float* denom  = (float*)(ws + 51601024);              //      1,024 B

    hipMemsetAsync(agg,    0, (size_t)N_NODES * F * sizeof(float), stream);
    hipMemsetAsync(segmax, 0, N_GRAPHS * sizeof(unsigned int), stream); // ordered-min
    hipMemsetAsync(denom,  0, N_GRAPHS * sizeof(float), stream);
    hipMemsetAsync(out,    0, (size_t)N_GRAPHS * F * sizeof(float), stream);

    scatter_add_edges<<<(N_EDGES * 64) / 256, 256, 0, stream>>>(x, src, dst, agg);
    transform_kernel<<<(N_NODES + 3) / 4, 256, 0, stream>>>(x, agg, Wg, bg, Wa, ba, h, scores);
    seg_max_kernel<<<(N_NODES + 255) / 256, 256, 0, stream>>>(scores, batch, segmax);
    pool_kernel<<<(N_NODES * 64) / 256, 256, 0, stream>>>(h, scores, batch, segmax, denom, out);
    finalize_kernel<<<(N_GRAPHS * F) / 256, 256, 0, stream>>>(out, denom);
}

// Round 2
// 558.873 us; speedup vs baseline: 1.8747x; 1.8747x over previous
//
#include <hip/hip_runtime.h>

#define N_NODES  100000
#define N_EDGES  1600000
#define N_GRAPHS 256
#define F        64

// ---------- 1. agg[dst] += x[src]  (wave per edge, lane = feature) ----------
__global__ __launch_bounds__(256) void scatter_add_edges(
        const float* __restrict__ x,
        const int*   __restrict__ src,
        const int*   __restrict__ dst,
        float*       __restrict__ agg) {
    unsigned int gid = blockIdx.x * 256u + threadIdx.x;
    int edge = (int)(gid >> 6);
    int lane = (int)(gid & 63u);
    if (edge >= N_EDGES) return;
    int s = src[edge];   // wave-uniform load (broadcast)
    int d = dst[edge];
    atomicAdd(&agg[d * F + lane], x[s * F + lane]);
}

// ---------- 2. h = relu((x+agg)@Wg + bg); scores = h@Wa + ba ----------
__global__ __launch_bounds__(256) void transform_kernel(
        const float* __restrict__ x,
        const float* __restrict__ agg,
        const float* __restrict__ Wg,   // [64,64] row-major (k, f)
        const float* __restrict__ bg,   // [64]
        const float* __restrict__ Wa,   // [64]
        const float* __restrict__ ba,   // [1]
        float*       __restrict__ h,
        float*       __restrict__ scores) {
    __shared__ float Wlds[F * F];
    __shared__ float blds[F];
    __shared__ float Walds[F];
    int tid = threadIdx.x;
    for (int i = tid; i < F * F; i += 256) Wlds[i] = Wg[i];
    if (tid < F) { blds[tid] = bg[tid]; Walds[tid] = Wa[tid]; }
    __syncthreads();

    int wave = tid >> 6;
    int lane = tid & 63;
    int n = blockIdx.x * 4 + wave;
    if (n >= N_NODES) return;

    float rowv = x[n * F + lane] + agg[n * F + lane];
    float acc = 0.f;
    #pragma unroll
    for (int k = 0; k < F; ++k) {
        float rk = __shfl(rowv, k, 64);
        acc += rk * Wlds[k * F + lane];   // lanes hit stride-1: 2-way bank alias, free
    }
    float hv = acc + blds[lane];
    hv = hv > 0.f ? hv : 0.f;
    h[n * F + lane] = hv;

    float p = hv * Walds[lane];
    #pragma unroll
    for (int off = 32; off > 0; off >>= 1)
        p += __shfl_down(p, off, 64);
    if (lane == 0) scores[n] = p + ba[0];
}

// ---------- 3. fused segmented softmax + weighted pool (atomic-free) ----------
__device__ __forceinline__ int lower_bound_i(const int* __restrict__ a, int n, int key) {
    int lo = 0, hi = n;
    while (lo < hi) {
        int mid = (lo + hi) >> 1;
        if (a[mid] < key) lo = mid + 1; else hi = mid;
    }
    return lo;
}

#define POOL_THREADS 512
#define POOL_WAVES   (POOL_THREADS / 64)

__global__ __launch_bounds__(POOL_THREADS) void attn_pool_kernel(
        const float* __restrict__ h,
        const float* __restrict__ scores,
        const int*   __restrict__ batch,
        float*       __restrict__ out) {
    int g = blockIdx.x;
    int tid  = threadIdx.x;
    int wave = tid >> 6;
    int lane = tid & 63;

    // segment bounds (batch is sorted) — wave-uniform binary search
    int lo = lower_bound_i(batch, N_NODES, g);
    int hi = lower_bound_i(batch, N_NODES, g + 1);

    // ---- pass 1: max over scores[lo:hi) ----
    __shared__ float red[POOL_THREADS];
    float m = -INFINITY;
    for (int n = lo + tid; n < hi; n += POOL_THREADS) m = fmaxf(m, scores[n]);
    red[tid] = m;
    __syncthreads();
    #pragma unroll
    for (int s = POOL_THREADS / 2; s > 0; s >>= 1) {
        if (tid < s) red[tid] = fmaxf(red[tid], red[tid + s]);
        __syncthreads();
    }
    m = red[0];
    __syncthreads();

    // ---- pass 2: acc[lane] += e * h[n,lane]; den += e ----
    float acc = 0.f, den = 0.f;
    for (int n = lo + wave; n < hi; n += POOL_WAVES) {
        float e = __expf(scores[n] - m);   // wave-uniform
        den += e;
        acc += e * h[n * F + lane];
    }

    __shared__ float accs[POOL_WAVES][F];
    __shared__ float dens[POOL_WAVES];
    accs[wave][lane] = acc;
    if (lane == 0) dens[wave] = den;
    __syncthreads();

    if (wave == 0) {
        float a = 0.f, d = 0.f;
        #pragma unroll
        for (int w = 0; w < POOL_WAVES; ++w) { a += accs[w][lane]; d += dens[w]; }
        out[g * F + lane] = (hi > lo) ? a / d : 0.f;
    }
}

extern "C" void kernel_launch(void* const* d_in, const int* in_sizes, int n_in,
                              void* d_out, int out_size, void* d_ws, size_t ws_size,
                              hipStream_t stream) {
    const float* x     = (const float*)d_in[0];
    const int*   ei    = (const int*)d_in[1];   // [2, N_EDGES]
    const int*   batch = (const int*)d_in[2];   // [N_NODES]
    const float* Wg    = (const float*)d_in[3];
    const float* bg    = (const float*)d_in[4];
    const float* Wa    = (const float*)d_in[5];
    const float* ba    = (const float*)d_in[6];
    float* out = (float*)d_out;

    const int* src = ei;
    const int* dst = ei + N_EDGES;

    // workspace layout (bytes)
    char* ws = (char*)d_ws;
    float* agg    = (float*)(ws);                         // 25,600,000 B
    float* h      = (float*)(ws + 25600000);              // 25,600,000 B
    float* scores = (float*)(ws + 51200000);              //    400,000 B

    hipMemsetAsync(agg, 0, (size_t)N_NODES * F * sizeof(float), stream);

    scatter_add_edges<<<(N_EDGES * 64) / 256, 256, 0, stream>>>(x, src, dst, agg);
    transform_kernel<<<(N_NODES + 3) / 4, 256, 0, stream>>>(x, agg, Wg, bg, Wa, ba, h, scores);
    attn_pool_kernel<<<N_GRAPHS, POOL_THREADS, 0, stream>>>(h, scores, batch, out);
}

// Round 3
// 465.295 us; speedup vs baseline: 2.2518x; 1.2011x over previous
//
#include <hip/hip_runtime.h>

#define N_NODES  100000
#define N_EDGES  1600000
#define N_GRAPHS 256
#define F        64

#define SCAN_B   1024
#define SCAN_NB  ((N_NODES + SCAN_B - 1) / SCAN_B)   // 98

// ---------- 1a. degree histogram over dst ----------
__global__ __launch_bounds__(256) void deg_kernel(
        const int* __restrict__ dst, int* __restrict__ deg) {
    int e = blockIdx.x * 256 + threadIdx.x;
    if (e >= N_EDGES) return;
    atomicAdd(&deg[dst[e]], 1);
}

// ---------- 1b. per-block inclusive scan of deg ----------
__global__ __launch_bounds__(SCAN_B) void scan1_kernel(
        const int* __restrict__ deg, int* __restrict__ excl, int* __restrict__ bsum) {
    __shared__ int tmp[SCAN_B];
    int tid = threadIdx.x;
    int i = blockIdx.x * SCAN_B + tid;
    int v = (i < N_NODES) ? deg[i] : 0;
    tmp[tid] = v;
    __syncthreads();
    #pragma unroll
    for (int o = 1; o < SCAN_B; o <<= 1) {
        int t = (tid >= o) ? tmp[tid - o] : 0;
        __syncthreads();
        tmp[tid] += t;
        __syncthreads();
    }
    if (i < N_NODES) excl[i] = tmp[tid] - v;        // exclusive within block
    if (tid == SCAN_B - 1) bsum[blockIdx.x] = tmp[tid];
}

// ---------- 1c. serial exclusive scan of 98 block sums ----------
__global__ void scan2_kernel(int* __restrict__ bsum) {
    int acc = 0;
    for (int i = 0; i < SCAN_NB; ++i) { int t = bsum[i]; bsum[i] = acc; acc += t; }
}

// ---------- 1d. add block offsets; init cursor ----------
__global__ __launch_bounds__(SCAN_B) void scan3_kernel(
        int* __restrict__ excl, const int* __restrict__ bsum, int* __restrict__ pos) {
    int i = blockIdx.x * SCAN_B + threadIdx.x;
    if (i >= N_NODES) return;
    int o = excl[i] + bsum[blockIdx.x];
    excl[i] = o;
    pos[i]  = o;
}

// ---------- 1e. CSR fill: eidx[slot] = src[e] grouped by dst ----------
__global__ __launch_bounds__(256) void fill_kernel(
        const int* __restrict__ src, const int* __restrict__ dst,
        int* __restrict__ pos, int* __restrict__ eidx) {
    int e = blockIdx.x * 256 + threadIdx.x;
    if (e >= N_EDGES) return;
    int slot = atomicAdd(&pos[dst[e]], 1);
    eidx[slot] = src[e];
}

// ---------- 2. fused gather + transform: rowv = x[n] + sum x[src]; h = relu(rowv@Wg+bg); score ----------
__global__ __launch_bounds__(256) void gather_transform_kernel(
        const float* __restrict__ x,
        const int*   __restrict__ off,
        const int*   __restrict__ deg,
        const int*   __restrict__ eidx,
        const float* __restrict__ Wg,   // [64,64] (k, f)
        const float* __restrict__ bg,
        const float* __restrict__ Wa,
        const float* __restrict__ ba,
        float*       __restrict__ h,
        float*       __restrict__ scores) {
    __shared__ float Wlds[F * F];
    __shared__ float blds[F];
    __shared__ float Walds[F];
    int tid = threadIdx.x;
    for (int i = tid; i < F * F; i += 256) Wlds[i] = Wg[i];
    if (tid < F) { blds[tid] = bg[tid]; Walds[tid] = Wa[tid]; }
    __syncthreads();

    int wave = tid >> 6;
    int lane = tid & 63;
    int n = blockIdx.x * 4 + wave;
    if (n >= N_NODES) return;

    int start = off[n];
    int end   = start + deg[n];

    float rowv = x[n * F + lane];
    for (int base = start; base < end; base += 64) {
        int cnt = end - base; if (cnt > 64) cnt = 64;
        int sl = (base + lane < end) ? eidx[base + lane] : 0;   // coalesced
        for (int j = 0; j < cnt; ++j) {
            int s = __shfl(sl, j, 64);
            rowv += x[s * F + lane];
        }
    }

    float acc = 0.f;
    #pragma unroll
    for (int k = 0; k < F; ++k) {
        float rk = __shfl(rowv, k, 64);
        acc += rk * Wlds[k * F + lane];
    }
    float hv = acc + blds[lane];
    hv = hv > 0.f ? hv : 0.f;
    h[n * F + lane] = hv;

    float p = hv * Walds[lane];
    #pragma unroll
    for (int o = 32; o > 0; o >>= 1)
        p += __shfl_down(p, o, 64);
    if (lane == 0) scores[n] = p + ba[0];
}

// ---------- 3. fused segmented softmax + weighted pool (atomic-free) ----------
__device__ __forceinline__ int lower_bound_i(const int* __restrict__ a, int n, int key) {
    int lo = 0, hi = n;
    while (lo < hi) {
        int mid = (lo + hi) >> 1;
        if (a[mid] < key) lo = mid + 1; else hi = mid;
    }
    return lo;
}

#define POOL_THREADS 512
#define POOL_WAVES   (POOL_THREADS / 64)

__global__ __launch_bounds__(POOL_THREADS) void attn_pool_kernel(
        const float* __restrict__ h,
        const float* __restrict__ scores,
        const int*   __restrict__ batch,
        float*       __restrict__ out) {
    int g = blockIdx.x;
    int tid  = threadIdx.x;
    int wave = tid >> 6;
    int lane = tid & 63;

    int lo = lower_bound_i(batch, N_NODES, g);
    int hi = lower_bound_i(batch, N_NODES, g + 1);

    __shared__ float red[POOL_THREADS];
    float m = -INFINITY;
    for (int n = lo + tid; n < hi; n += POOL_THREADS) m = fmaxf(m, scores[n]);
    red[tid] = m;
    __syncthreads();
    #pragma unroll
    for (int s = POOL_THREADS / 2; s > 0; s >>= 1) {
        if (tid < s) red[tid] = fmaxf(red[tid], red[tid + s]);
        __syncthreads();
    }
    m = red[0];
    __syncthreads();

    float acc = 0.f, den = 0.f;
    for (int n = lo + wave; n < hi; n += POOL_WAVES) {
        float e = __expf(scores[n] - m);
        den += e;
        acc += e * h[n * F + lane];
    }

    __shared__ float accs[POOL_WAVES][F];
    __shared__ float dens[POOL_WAVES];
    accs[wave][lane] = acc;
    if (lane == 0) dens[wave] = den;
    __syncthreads();

    if (wave == 0) {
        float a = 0.f, d = 0.f;
        #pragma unroll
        for (int w = 0; w < POOL_WAVES; ++w) { a += accs[w][lane]; d += dens[w]; }
        out[g * F + lane] = (hi > lo) ? a / d : 0.f;
    }
}

extern "C" void kernel_launch(void* const* d_in, const int* in_sizes, int n_in,
                              void* d_out, int out_size, void* d_ws, size_t ws_size,
                              hipStream_t stream) {
    const float* x     = (const float*)d_in[0];
    const int*   ei    = (const int*)d_in[1];   // [2, N_EDGES]
    const int*   batch = (const int*)d_in[2];   // [N_NODES]
    const float* Wg    = (const float*)d_in[3];
    const float* bg    = (const float*)d_in[4];
    const float* Wa    = (const float*)d_in[5];
    const float* ba    = (const float*)d_in[6];
    float* out = (float*)d_out;

    const int* src = ei;
    const int* dst = ei + N_EDGES;

    // workspace layout (bytes, all 256-aligned)
    char* ws = (char*)d_ws;
    int*   deg    = (int*)(ws);                    //   400,000 B
    int*   off    = (int*)(ws +   400128);         //   400,000 B
    int*   pos    = (int*)(ws +   800256);         //   400,000 B
    int*   bsum   = (int*)(ws +  1200384);         //       392 B
    int*   eidx   = (int*)(ws +  1200896);         // 6,400,000 B
    float* h      = (float*)(ws +  7601152);       // 25,600,000 B
    float* scores = (float*)(ws + 33201152);       //   400,000 B

    hipMemsetAsync(deg, 0, N_NODES * sizeof(int), stream);

    deg_kernel  <<<(N_EDGES + 255) / 256, 256, 0, stream>>>(dst, deg);
    scan1_kernel<<<SCAN_NB, SCAN_B, 0, stream>>>(deg, off, bsum);
    scan2_kernel<<<1, 1, 0, stream>>>(bsum);
    scan3_kernel<<<SCAN_NB, SCAN_B, 0, stream>>>(off, bsum, pos);
    fill_kernel <<<(N_EDGES + 255) / 256, 256, 0, stream>>>(src, dst, pos, eidx);
    gather_transform_kernel<<<(N_NODES + 3) / 4, 256, 0, stream>>>(
        x, off, deg, eidx, Wg, bg, Wa, ba, h, scores);
    attn_pool_kernel<<<N_GRAPHS, POOL_THREADS, 0, stream>>>(h, scores, batch, out);
}

// Round 4
// 415.341 us; speedup vs baseline: 2.5226x; 1.1203x over previous
//
#include <hip/hip_runtime.h>

#define N_NODES  100000
#define N_EDGES  1600000
#define N_GRAPHS 256
#define F        64

#define SCAN_B   1024
#define SCAN_NB  ((N_NODES + SCAN_B - 1) / SCAN_B)   // 98

// ---------- 1a. degree histogram over dst ----------
__global__ __launch_bounds__(256) void deg_kernel(
        const int* __restrict__ dst, int* __restrict__ deg) {
    int e = blockIdx.x * 256 + threadIdx.x;
    if (e >= N_EDGES) return;
    atomicAdd(&deg[dst[e]], 1);
}

// ---------- 1b. per-block inclusive scan of deg ----------
__global__ __launch_bounds__(SCAN_B) void scan1_kernel(
        const int* __restrict__ deg, int* __restrict__ excl, int* __restrict__ bsum) {
    __shared__ int tmp[SCAN_B];
    int tid = threadIdx.x;
    int i = blockIdx.x * SCAN_B + tid;
    int v = (i < N_NODES) ? deg[i] : 0;
    tmp[tid] = v;
    __syncthreads();
    #pragma unroll
    for (int o = 1; o < SCAN_B; o <<= 1) {
        int t = (tid >= o) ? tmp[tid - o] : 0;
        __syncthreads();
        tmp[tid] += t;
        __syncthreads();
    }
    if (i < N_NODES) excl[i] = tmp[tid] - v;        // exclusive within block
    if (tid == SCAN_B - 1) bsum[blockIdx.x] = tmp[tid];
}

// ---------- 1c. parallel exclusive scan of 98 block sums (1 block) ----------
__global__ __launch_bounds__(128) void scan2_kernel(int* __restrict__ bsum) {
    __shared__ int t[128];
    int tid = threadIdx.x;
    int v = (tid < SCAN_NB) ? bsum[tid] : 0;
    t[tid] = v;
    __syncthreads();
    #pragma unroll
    for (int o = 1; o < 128; o <<= 1) {
        int u = (tid >= o) ? t[tid - o] : 0;
        __syncthreads();
        t[tid] += u;
        __syncthreads();
    }
    if (tid < SCAN_NB) bsum[tid] = t[tid] - v;
}

// ---------- 1d. add block offsets; init cursor ----------
__global__ __launch_bounds__(SCAN_B) void scan3_kernel(
        int* __restrict__ excl, const int* __restrict__ bsum, int* __restrict__ pos) {
    int i = blockIdx.x * SCAN_B + threadIdx.x;
    if (i >= N_NODES) return;
    int o = excl[i] + bsum[blockIdx.x];
    excl[i] = o;
    pos[i]  = o;
}

// ---------- 1e. CSR fill: eidx[slot] = src[e] grouped by dst ----------
__global__ __launch_bounds__(256) void fill_kernel(
        const int* __restrict__ src, const int* __restrict__ dst,
        int* __restrict__ pos, int* __restrict__ eidx) {
    int e = blockIdx.x * 256 + threadIdx.x;
    if (e >= N_EDGES) return;
    int slot = atomicAdd(&pos[dst[e]], 1);
    eidx[slot] = src[e];
}

// ---------- 2. fused gather + transform (float4 gather, 4 rows per wave-iter) ----------
__global__ __launch_bounds__(256) void gather_transform_kernel(
        const float* __restrict__ x,
        const int*   __restrict__ off,
        const int*   __restrict__ deg,
        const int*   __restrict__ eidx,
        const float* __restrict__ Wg,   // [64,64] (k, f)
        const float* __restrict__ bg,
        const float* __restrict__ Wa,
        const float* __restrict__ ba,
        float*       __restrict__ h,
        float*       __restrict__ scores) {
    __shared__ float Wlds[F * F];
    __shared__ float blds[F];
    __shared__ float Walds[F];
    int tid = threadIdx.x;
    {
        const float4* Wg4 = (const float4*)Wg;
        float4* Wl4 = (float4*)Wlds;
        #pragma unroll
        for (int i = 0; i < 4; ++i) Wl4[tid + 256 * i] = Wg4[tid + 256 * i];
        if (tid < F) { blds[tid] = bg[tid]; Walds[tid] = Wa[tid]; }
    }
    __syncthreads();

    int wave = tid >> 6;
    int lane = tid & 63;
    int grp  = lane >> 4;   // 0..3: which row within a 4-row batch
    int c    = lane & 15;   // float4 chunk within a row

    int n = blockIdx.x * 4 + wave;   // N_NODES % 4 == 0, no guard needed

    int start = off[n];
    int end   = start + deg[n];

    const float4* x4 = (const float4*)x;
    float4 acc4 = make_float4(0.f, 0.f, 0.f, 0.f);

    for (int base = start; base < end; base += 64) {
        int jmax = end - base; if (jmax > 64) jmax = 64;
        int sl = (base + lane < end) ? eidx[base + lane] : 0;   // coalesced
        for (int j = 0; j < jmax; j += 4) {
            int el = j + grp;
            int s  = __shfl(sl, el, 64);
            if (el < jmax) {
                float4 v = x4[s * 16 + c];   // 16 B/lane, 4 rows per instruction
                acc4.x += v.x; acc4.y += v.y; acc4.z += v.z; acc4.w += v.w;
            }
        }
    }

    // cross-group butterfly: combine the 4 partial row-sums
    #pragma unroll
    for (int o = 16; o <= 32; o <<= 1) {
        acc4.x += __shfl_xor(acc4.x, o, 64);
        acc4.y += __shfl_xor(acc4.y, o, 64);
        acc4.z += __shfl_xor(acc4.z, o, 64);
        acc4.w += __shfl_xor(acc4.w, o, 64);
    }
    // add self row (each lane holds chunk c of the complete row now)
    {
        float4 v = x4[n * 16 + c];
        acc4.x += v.x; acc4.y += v.y; acc4.z += v.z; acc4.w += v.w;
    }

    // matmul: rowv element k lives in lane k>>2, component k&3 (all groups identical)
    float re[4] = {acc4.x, acc4.y, acc4.z, acc4.w};
    float accf = 0.f;
    #pragma unroll
    for (int k = 0; k < F; ++k) {
        float rk = __shfl(re[k & 3], k >> 2, 64);
        accf += rk * Wlds[k * F + lane];
    }
    float hv = accf + blds[lane];
    hv = hv > 0.f ? hv : 0.f;
    h[n * F + lane] = hv;

    float p = hv * Walds[lane];
    #pragma unroll
    for (int o = 32; o > 0; o >>= 1)
        p += __shfl_down(p, o, 64);
    if (lane == 0) scores[n] = p + ba[0];
}

// ---------- 3. fused segmented softmax + weighted pool (atomic-free, float4) ----------
__device__ __forceinline__ int lower_bound_i(const int* __restrict__ a, int n, int key) {
    int lo = 0, hi = n;
    while (lo < hi) {
        int mid = (lo + hi) >> 1;
        if (a[mid] < key) lo = mid + 1; else hi = mid;
    }
    return lo;
}

#define POOL_THREADS 512
#define POOL_WAVES   (POOL_THREADS / 64)

__global__ __launch_bounds__(POOL_THREADS) void attn_pool_kernel(
        const float* __restrict__ h,
        const float* __restrict__ scores,
        const int*   __restrict__ batch,
        float*       __restrict__ out) {
    int g = blockIdx.x;
    int tid  = threadIdx.x;
    int wave = tid >> 6;
    int lane = tid & 63;
    int grp  = lane >> 4;
    int c    = lane & 15;

    int lo = lower_bound_i(batch, N_NODES, g);
    int hi = lower_bound_i(batch, N_NODES, g + 1);

    // ---- pass 1: max over scores[lo:hi) ----
    __shared__ float red[POOL_THREADS];
    float m = -INFINITY;
    for (int n = lo + tid; n < hi; n += POOL_THREADS) m = fmaxf(m, scores[n]);
    red[tid] = m;
    __syncthreads();
    #pragma unroll
    for (int s = POOL_THREADS / 2; s > 0; s >>= 1) {
        if (tid < s) red[tid] = fmaxf(red[tid], red[tid + s]);
        __syncthreads();
    }
    m = red[0];
    __syncthreads();

    // ---- pass 2: float4 weighted accumulation, 4 nodes per wave-iter ----
    const float4* h4 = (const float4*)h;
    float4 acc = make_float4(0.f, 0.f, 0.f, 0.f);
    float den = 0.f;
    for (int base = lo + wave * 4; base < hi; base += POOL_WAVES * 4) {
        int n = base + grp;
        if (n < hi) {
            float e = __expf(scores[n] - m);
            den += e;
            float4 v = h4[n * 16 + c];
            acc.x += e * v.x; acc.y += e * v.y; acc.z += e * v.z; acc.w += e * v.w;
        }
    }
    #pragma unroll
    for (int o = 16; o <= 32; o <<= 1) {
        acc.x += __shfl_xor(acc.x, o, 64);
        acc.y += __shfl_xor(acc.y, o, 64);
        acc.z += __shfl_xor(acc.z, o, 64);
        acc.w += __shfl_xor(acc.w, o, 64);
        den   += __shfl_xor(den,   o, 64);
    }

    __shared__ float4 accs4[POOL_WAVES][16];
    __shared__ float  dens[POOL_WAVES];
    if (lane < 16) accs4[wave][c] = acc;
    if (lane == 0) dens[wave] = den;
    __syncthreads();

    if (wave == 0) {
        const float* accsf = (const float*)accs4;   // [POOL_WAVES][64]
        float a = 0.f, d = 0.f;
        #pragma unroll
        for (int w = 0; w < POOL_WAVES; ++w) { a += accsf[w * F + lane]; d += dens[w]; }
        out[g * F + lane] = (hi > lo) ? a / d : 0.f;
    }
}

extern "C" void kernel_launch(void* const* d_in, const int* in_sizes, int n_in,
                              void* d_out, int out_size, void* d_ws, size_t ws_size,
                              hipStream_t stream) {
    const float* x     = (const float*)d_in[0];
    const int*   ei    = (const int*)d_in[1];   // [2, N_EDGES]
    const int*   batch = (const int*)d_in[2];   // [N_NODES]
    const float* Wg    = (const float*)d_in[3];
    const float* bg    = (const float*)d_in[4];
    const float* Wa    = (const float*)d_in[5];
    const float* ba    = (const float*)d_in[6];
    float* out = (float*)d_out;

    const int* src = ei;
    const int* dst = ei + N_EDGES;

    // workspace layout (bytes, all 256-aligned)
    char* ws = (char*)d_ws;
    int*   deg    = (int*)(ws);                    //   400,000 B
    int*   off    = (int*)(ws +   400128);         //   400,000 B
    int*   pos    = (int*)(ws +   800256);         //   400,000 B
    int*   bsum   = (int*)(ws +  1200384);         //       392 B
    int*   eidx   = (int*)(ws +  1200896);         // 6,400,000 B
    float* h      = (float*)(ws +  7601152);       // 25,600,000 B
    float* scores = (float*)(ws + 33201152);       //   400,000 B

    hipMemsetAsync(deg, 0, N_NODES * sizeof(int), stream);

    deg_kernel  <<<(N_EDGES + 255) / 256, 256, 0, stream>>>(dst, deg);
    scan1_kernel<<<SCAN_NB, SCAN_B, 0, stream>>>(deg, off, bsum);
    scan2_kernel<<<1, 128, 0, stream>>>(bsum);
    scan3_kernel<<<SCAN_NB, SCAN_B, 0, stream>>>(off, bsum, pos);
    fill_kernel <<<(N_EDGES + 255) / 256, 256, 0, stream>>>(src, dst, pos, eidx);
    gather_transform_kernel<<<N_NODES / 4, 256, 0, stream>>>(
        x, off, deg, eidx, Wg, bg, Wa, ba, h, scores);
    attn_pool_kernel<<<N_GRAPHS, POOL_THREADS, 0, stream>>>(h, scores, batch, out);
}

// Round 5
// 377.999 us; speedup vs baseline: 2.7718x; 1.0988x over previous
//
#include <hip/hip_runtime.h>

#define N_NODES  100000
#define N_EDGES  1600000
#define N_GRAPHS 256
#define F        64

#define SCAN_B   1024
#define SCAN_NB  ((N_NODES + SCAN_B - 1) / SCAN_B)   // 98

// ---------- 1a. degree histogram over dst ----------
__global__ __launch_bounds__(256) void deg_kernel(
        const int* __restrict__ dst, int* __restrict__ deg) {
    int e = blockIdx.x * 256 + threadIdx.x;
    if (e >= N_EDGES) return;
    atomicAdd(&deg[dst[e]], 1);
}

// ---------- 1b. per-block inclusive scan of deg ----------
__global__ __launch_bounds__(SCAN_B) void scan1_kernel(
        const int* __restrict__ deg, int* __restrict__ excl, int* __restrict__ bsum) {
    __shared__ int tmp[SCAN_B];
    int tid = threadIdx.x;
    int i = blockIdx.x * SCAN_B + tid;
    int v = (i < N_NODES) ? deg[i] : 0;
    tmp[tid] = v;
    __syncthreads();
    #pragma unroll
    for (int o = 1; o < SCAN_B; o <<= 1) {
        int t = (tid >= o) ? tmp[tid - o] : 0;
        __syncthreads();
        tmp[tid] += t;
        __syncthreads();
    }
    if (i < N_NODES) excl[i] = tmp[tid] - v;        // exclusive within block
    if (tid == SCAN_B - 1) bsum[blockIdx.x] = tmp[tid];
}

// ---------- 1c. parallel exclusive scan of 98 block sums (1 block) ----------
__global__ __launch_bounds__(128) void scan2_kernel(int* __restrict__ bsum) {
    __shared__ int t[128];
    int tid = threadIdx.x;
    int v = (tid < SCAN_NB) ? bsum[tid] : 0;
    t[tid] = v;
    __syncthreads();
    #pragma unroll
    for (int o = 1; o < 128; o <<= 1) {
        int u = (tid >= o) ? t[tid - o] : 0;
        __syncthreads();
        t[tid] += u;
        __syncthreads();
    }
    if (tid < SCAN_NB) bsum[tid] = t[tid] - v;
}

// ---------- 1d. add block offsets; init cursor ----------
__global__ __launch_bounds__(SCAN_B) void scan3_kernel(
        int* __restrict__ excl, const int* __restrict__ bsum, int* __restrict__ pos) {
    int i = blockIdx.x * SCAN_B + threadIdx.x;
    if (i >= N_NODES) return;
    int o = excl[i] + bsum[blockIdx.x];
    excl[i] = o;
    pos[i]  = o;
}

// ---------- 1e. CSR fill: eidx[slot] = src[e] grouped by dst ----------
__global__ __launch_bounds__(256) void fill_kernel(
        const int* __restrict__ src, const int* __restrict__ dst,
        int* __restrict__ pos, int* __restrict__ eidx) {
    int e = blockIdx.x * 256 + threadIdx.x;
    if (e >= N_EDGES) return;
    int slot = atomicAdd(&pos[dst[e]], 1);
    eidx[slot] = src[e];
}

// ---------- 2. fused gather + transform ----------
// Grid-stride wave-per-node. W columns live in VGPRs (wcol[64]); row broadcast
// via v_readlane (VALU) instead of ds_bpermute+LDS — near-zero LDS pipe usage.
#define GT_BLOCKS 1024
#define GT_WAVES  (GT_BLOCKS * 4)

__global__ __launch_bounds__(256, 4) void gather_transform_kernel(
        const float* __restrict__ x,
        const int*   __restrict__ off,
        const int*   __restrict__ deg,
        const int*   __restrict__ eidx,
        const float* __restrict__ Wg,   // [64,64] (k, f)
        const float* __restrict__ bg,
        const float* __restrict__ Wa,
        const float* __restrict__ ba,
        float*       __restrict__ h,
        float*       __restrict__ scores) {
    int tid  = threadIdx.x;
    int lane = tid & 63;
    int grp  = lane >> 4;   // 0..3: row within a 4-row gather batch
    int c    = lane & 15;   // float4 chunk within a row
    int waveId = blockIdx.x * 4 + (tid >> 6);

    // W[k][lane] for all k, held in registers; amortized over ~24 nodes/wave
    float wcol[F];
    #pragma unroll
    for (int k = 0; k < F; ++k) wcol[k] = Wg[k * F + lane];
    float bgl = bg[lane];
    float wal = Wa[lane];
    float ba0 = ba[0];

    const float4* x4 = (const float4*)x;

    for (int n = waveId; n < N_NODES; n += GT_WAVES) {
        int start = off[n];
        int end   = start + deg[n];

        float4 a = make_float4(0.f, 0.f, 0.f, 0.f);
        for (int base = start; base < end; base += 64) {
            int jmax = end - base; if (jmax > 64) jmax = 64;
            int sl = (base + lane < end) ? eidx[base + lane] : 0;   // coalesced
            for (int j = 0; j < jmax; j += 4) {
                int el = j + grp;
                int s  = __shfl(sl, el, 64);
                if (el < jmax) {
                    float4 v = x4[s * 16 + c];   // 4 rows / wave-instruction
                    a.x += v.x; a.y += v.y; a.z += v.z; a.w += v.w;
                }
            }
        }
        // combine the 4 group-partials: every lane ends with the full row chunk c
        #pragma unroll
        for (int o = 16; o <= 32; o <<= 1) {
            a.x += __shfl_xor(a.x, o, 64);
            a.y += __shfl_xor(a.y, o, 64);
            a.z += __shfl_xor(a.z, o, 64);
            a.w += __shfl_xor(a.w, o, 64);
        }
        { float4 v = x4[n * 16 + c]; a.x += v.x; a.y += v.y; a.z += v.z; a.w += v.w; }

        // matmul: row element k lives in lane k>>2, component k&3
        float re[4] = {a.x, a.y, a.z, a.w};
        float acc0 = 0.f, acc1 = 0.f, acc2 = 0.f, acc3 = 0.f;
        #pragma unroll
        for (int k = 0; k < F; k += 4) {
            float r0 = __int_as_float(__builtin_amdgcn_readlane(__float_as_int(re[0]), k >> 2));
            float r1 = __int_as_float(__builtin_amdgcn_readlane(__float_as_int(re[1]), k >> 2));
            float r2 = __int_as_float(__builtin_amdgcn_readlane(__float_as_int(re[2]), k >> 2));
            float r3 = __int_as_float(__builtin_amdgcn_readlane(__float_as_int(re[3]), k >> 2));
            acc0 += r0 * wcol[k + 0];
            acc1 += r1 * wcol[k + 1];
            acc2 += r2 * wcol[k + 2];
            acc3 += r3 * wcol[k + 3];
        }
        float hv = (acc0 + acc1) + (acc2 + acc3) + bgl;
        hv = hv > 0.f ? hv : 0.f;
        h[n * F + lane] = hv;

        float p = hv * wal;
        #pragma unroll
        for (int o = 32; o > 0; o >>= 1)
            p += __shfl_down(p, o, 64);
        if (lane == 0) scores[n] = p + ba0;
    }
}

// ---------- 3. fused segmented softmax + weighted pool (atomic-free, float4) ----------
__device__ __forceinline__ int lower_bound_i(const int* __restrict__ a, int n, int key) {
    int lo = 0, hi = n;
    while (lo < hi) {
        int mid = (lo + hi) >> 1;
        if (a[mid] < key) lo = mid + 1; else hi = mid;
    }
    return lo;
}

#define POOL_THREADS 512
#define POOL_WAVES   (POOL_THREADS / 64)

__global__ __launch_bounds__(POOL_THREADS) void attn_pool_kernel(
        const float* __restrict__ h,
        const float* __restrict__ scores,
        const int*   __restrict__ batch,
        float*       __restrict__ out) {
    int g = blockIdx.x;
    int tid  = threadIdx.x;
    int wave = tid >> 6;
    int lane = tid & 63;
    int grp  = lane >> 4;
    int c    = lane & 15;

    int lo = lower_bound_i(batch, N_NODES, g);
    int hi = lower_bound_i(batch, N_NODES, g + 1);

    __shared__ float red[POOL_THREADS];
    float m = -INFINITY;
    for (int n = lo + tid; n < hi; n += POOL_THREADS) m = fmaxf(m, scores[n]);
    red[tid] = m;
    __syncthreads();
    #pragma unroll
    for (int s = POOL_THREADS / 2; s > 0; s >>= 1) {
        if (tid < s) red[tid] = fmaxf(red[tid], red[tid + s]);
        __syncthreads();
    }
    m = red[0];
    __syncthreads();

    const float4* h4 = (const float4*)h;
    float4 acc = make_float4(0.f, 0.f, 0.f, 0.f);
    float den = 0.f;
    for (int base = lo + wave * 4; base < hi; base += POOL_WAVES * 4) {
        int n = base + grp;
        if (n < hi) {
            float e = __expf(scores[n] - m);
            den += e;
            float4 v = h4[n * 16 + c];
            acc.x += e * v.x; acc.y += e * v.y; acc.z += e * v.z; acc.w += e * v.w;
        }
    }
    #pragma unroll
    for (int o = 16; o <= 32; o <<= 1) {
        acc.x += __shfl_xor(acc.x, o, 64);
        acc.y += __shfl_xor(acc.y, o, 64);
        acc.z += __shfl_xor(acc.z, o, 64);
        acc.w += __shfl_xor(acc.w, o, 64);
        den   += __shfl_xor(den,   o, 64);
    }

    __shared__ float4 accs4[POOL_WAVES][16];
    __shared__ float  dens[POOL_WAVES];
    if (lane < 16) accs4[wave][c] = acc;
    if (lane == 0) dens[wave] = den;
    __syncthreads();

    if (wave == 0) {
        const float* accsf = (const float*)accs4;   // [POOL_WAVES][64]
        float a = 0.f, d = 0.f;
        #pragma unroll
        for (int w = 0; w < POOL_WAVES; ++w) { a += accsf[w * F + lane]; d += dens[w]; }
        out[g * F + lane] = (hi > lo) ? a / d : 0.f;
    }
}

extern "C" void kernel_launch(void* const* d_in, const int* in_sizes, int n_in,
                              void* d_out, int out_size, void* d_ws, size_t ws_size,
                              hipStream_t stream) {
    const float* x     = (const float*)d_in[0];
    const int*   ei    = (const int*)d_in[1];   // [2, N_EDGES]
    const int*   batch = (const int*)d_in[2];   // [N_NODES]
    const float* Wg    = (const float*)d_in[3];
    const float* bg    = (const float*)d_in[4];
    const float* Wa    = (const float*)d_in[5];
    const float* ba    = (const float*)d_in[6];
    float* out = (float*)d_out;

    const int* src = ei;
    const int* dst = ei + N_EDGES;

    // workspace layout (bytes, all 256-aligned)
    char* ws = (char*)d_ws;
    int*   deg    = (int*)(ws);                    //   400,000 B
    int*   off    = (int*)(ws +   400128);         //   400,000 B
    int*   pos    = (int*)(ws +   800256);         //   400,000 B
    int*   bsum   = (int*)(ws +  1200384);         //       392 B
    int*   eidx   = (int*)(ws +  1200896);         // 6,400,000 B
    float* h      = (float*)(ws +  7601152);       // 25,600,000 B
    float* scores = (float*)(ws + 33201152);       //   400,000 B

    hipMemsetAsync(deg, 0, N_NODES * sizeof(int), stream);

    deg_kernel  <<<(N_EDGES + 255) / 256, 256, 0, stream>>>(dst, deg);
    scan1_kernel<<<SCAN_NB, SCAN_B, 0, stream>>>(deg, off, bsum);
    scan2_kernel<<<1, 128, 0, stream>>>(bsum);
    scan3_kernel<<<SCAN_NB, SCAN_B, 0, stream>>>(off, bsum, pos);
    fill_kernel <<<(N_EDGES + 255) / 256, 256, 0, stream>>>(src, dst, pos, eidx);
    gather_transform_kernel<<<GT_BLOCKS, 256, 0, stream>>>(
        x, off, deg, eidx, Wg, bg, Wa, ba, h, scores);
    attn_pool_kernel<<<N_GRAPHS, POOL_THREADS, 0, stream>>>(h, scores, batch, out);
}